// Round 20
// baseline (1167.612 us; speedup 1.0000x reference)
//
#include <hip/hip_runtime.h>
#include <math.h>

#define H 1024
#define SEQ 2048
#define NHEADS 16
#define HSZ 64
#define NROWS 8192            // B*S = 4*2048
constexpr float SCALE = 0.125f;          // 1/sqrt(64)
constexpr float LOG2E = 1.44269504088896f;

typedef unsigned short u16;
typedef __attribute__((ext_vector_type(8))) short bf16x8;   // 8 bf16 (4 VGPRs)
typedef __attribute__((ext_vector_type(4))) float f32x4;    // 4 fp32
typedef __attribute__((ext_vector_type(16))) float f32x16;  // 32x32 acc
typedef __attribute__((ext_vector_type(4))) unsigned int u32x4;

__device__ __forceinline__ u16 f2bf(float f) {
  unsigned int u = __builtin_bit_cast(unsigned int, f);
  u = (u + 0x7fffu + ((u >> 16) & 1u)) >> 16;  // RNE
  return (u16)u;
}
__device__ __forceinline__ float bf2f(u16 h) {
  return __builtin_bit_cast(float, (unsigned int)h << 16);
}

// async global->LDS, 16B per lane. LDS dest = wave-uniform base + lane*16.
__device__ __forceinline__ void gload_lds16(const void* g, void* l) {
  unsigned long long ga = (unsigned long long)g;
  unsigned int la = (unsigned int)(unsigned long long)l;
  __builtin_amdgcn_global_load_lds(
      (const __attribute__((address_space(1))) unsigned int*)ga,
      (__attribute__((address_space(3))) unsigned int*)la, 16, 0, 0);
}

// ---------------------------------------------------------------------------
// Merged cast kernel (R18-verified): y=0 casts X, y=1..4 the weights.
// ---------------------------------------------------------------------------
__global__ __launch_bounds__(256) void cast_all(
    const float* __restrict__ x, const float* __restrict__ Wq,
    const float* __restrict__ Wk, const float* __restrict__ Wv,
    const float* __restrict__ Wo, u16* __restrict__ Xb, u16* __restrict__ Wqb,
    u16* __restrict__ Wkb, u16* __restrict__ Wvb, u16* __restrict__ Wob) {
  const int which = blockIdx.y;
  const float* src;
  u16* dst;
  int n4;
  if (which == 0) {
    src = x; dst = Xb; n4 = NROWS * H / 4;
  } else if (which == 1) {
    src = Wq; dst = Wqb; n4 = H * H / 4;
  } else if (which == 2) {
    src = Wk; dst = Wkb; n4 = H * H / 4;
  } else if (which == 3) {
    src = Wv; dst = Wvb; n4 = H * H / 4;
  } else {
    src = Wo; dst = Wob; n4 = H * H / 4;
  }
  for (int i = blockIdx.x * blockDim.x + threadIdx.x; i < n4;
       i += gridDim.x * blockDim.x) {
    float4 v = ((const float4*)src)[i];
    ushort4 o;
    o.x = f2bf(v.x); o.y = f2bf(v.y); o.z = f2bf(v.z); o.w = f2bf(v.w);
    ((ushort4*)dst)[i] = o;
  }
}

// ---------------------------------------------------------------------------
// MFMA GEMM (verified R4; R12 grid: blockIdx.x = row stripe -> XCD-local).
// ---------------------------------------------------------------------------
__device__ __forceinline__ void stage_tile(const u16* __restrict__ gbase,
                                           int row0, int k0,
                                           u16* __restrict__ lds, int t) {
  const int rl = t >> 3;
  const int sl = t & 7;
#pragma unroll
  for (int c = 0; c < 4; ++c) {
    const int r = c * 32 + rl;
    const int slot = sl ^ (r & 7);
    gload_lds16(gbase + (size_t)(row0 + r) * H + k0 + slot * 8,
                lds + (size_t)t * 8 + c * 2048);
  }
}

__device__ __forceinline__ void wave_frags(const u16* __restrict__ Ts, int w64,
                                           int lr, int g, int kk,
                                           bf16x8 f[4]) {
#pragma unroll
  for (int m = 0; m < 4; ++m) {
    const int row = w64 + m * 16 + lr;
    const int slot = (4 * kk + g) ^ (row & 7);
    f[m] = *(const bf16x8*)&Ts[row * 64 + slot * 8];
  }
}

__device__ __forceinline__ void wave_mma_step(const u16* As, const u16* Bs,
                                              int wr, int wc, int lr, int g,
                                              f32x4 acc[4][4]) {
#pragma unroll
  for (int kk = 0; kk < 2; ++kk) {
    bf16x8 af[4], bfr[4];
    wave_frags(As, wr * 64, lr, g, kk, af);
    wave_frags(Bs, wc * 64, lr, g, kk, bfr);
#pragma unroll
    for (int m = 0; m < 4; ++m)
#pragma unroll
      for (int n = 0; n < 4; ++n)
        acc[m][n] = __builtin_amdgcn_mfma_f32_16x16x32_bf16(af[m], bfr[n],
                                                            acc[m][n], 0, 0, 0);
  }
}

// QKV projection. z=0: Q (scaled, row-major [B,NH,S,HS]); z=1: K (row-major);
// z=2: V written DIRECTLY in transposed [B,NH,HS,S] layout (ushort4 stores).
__global__ __launch_bounds__(256) void qkv_mfma(
    const u16* __restrict__ Xb, const u16* __restrict__ Wqb,
    const u16* __restrict__ Wkb, const u16* __restrict__ Wvb,
    const float* __restrict__ bq, const float* __restrict__ bk,
    const float* __restrict__ bv, u16* __restrict__ Qo, u16* __restrict__ Ko,
    u16* __restrict__ VTo) {
  __shared__ u16 As[128 * 64];
  __shared__ u16 Bs[128 * 64];

  const u16* Wb;
  const float* bias;
  float scale = 1.0f;
  if (blockIdx.z == 0) {
    Wb = Wqb; bias = bq; scale = SCALE * LOG2E;  // exp2-domain scores
  } else if (blockIdx.z == 1) {
    Wb = Wkb; bias = bk;
  } else {
    Wb = Wvb; bias = bv;
  }

  const int t = threadIdx.x;
  const int lane = t & 63, w = t >> 6;
  const int lr = lane & 15, g = lane >> 4;
  const int wr = w >> 1, wc = w & 1;
  const int row0 = blockIdx.x * 128;  // rows on fastest dim (XCD-local)
  const int col0 = blockIdx.y * 128;

  f32x4 acc[4][4];
#pragma unroll
  for (int m = 0; m < 4; ++m)
#pragma unroll
    for (int n = 0; n < 4; ++n) acc[m][n] = (f32x4){0.f, 0.f, 0.f, 0.f};

  for (int k0 = 0; k0 < H; k0 += 64) {
    __syncthreads();
    stage_tile(Xb, row0, k0, As, t);
    stage_tile(Wb, col0, k0, Bs, t);
    __syncthreads();
    wave_mma_step(As, Bs, wr, wc, lr, g, acc);
  }

  if (blockIdx.z == 2) {
    // V -> VT [B,NH,HS,S]: 4 consecutive s per acc vector -> ushort4
#pragma unroll
    for (int m = 0; m < 4; ++m) {
      const int row = row0 + wr * 64 + m * 16 + 4 * g;  // s0 (mult of 4)
      const int b = row >> 11, s = row & 2047;
#pragma unroll
      for (int n = 0; n < 4; ++n) {
        const int col = col0 + wc * 64 + n * 16 + lr;
        const int head = col >> 6, hs = col & 63;
        const float bb = bias[col];
        ushort4 sv;
        sv.x = f2bf(acc[m][n][0] + bb);
        sv.y = f2bf(acc[m][n][1] + bb);
        sv.z = f2bf(acc[m][n][2] + bb);
        sv.w = f2bf(acc[m][n][3] + bb);
        *(ushort4*)&VTo[((size_t)(b * NHEADS + head) * HSZ + hs) * SEQ + s] =
            sv;
      }
    }
  } else {
    u16* Y = blockIdx.z == 0 ? Qo : Ko;
#pragma unroll
    for (int m = 0; m < 4; ++m) {
      const int row = row0 + wr * 64 + m * 16 + 4 * g;
#pragma unroll
      for (int n = 0; n < 4; ++n) {
        const int col = col0 + wc * 64 + n * 16 + lr;
        const int head = col >> 6, hs = col & 63;
        const float bb = bias[col];
#pragma unroll
        for (int r = 0; r < 4; ++r) {
          const int rr = row + r;
          const int b = rr >> 11, s = rr & 2047;
          Y[((size_t)(b * NHEADS + head) * SEQ + s) * HSZ + hs] =
              f2bf((acc[m][n][r] + bb) * scale);
        }
      }
    }
  }
}

// Out projection: plain bf16 GEMM (R17), fp32 output + bias.
__global__ __launch_bounds__(256) void out_mfma(
    const u16* __restrict__ Ab, const u16* __restrict__ Bb,
    const float* __restrict__ bias, float* __restrict__ Y) {
  __shared__ u16 As[128 * 64];
  __shared__ u16 Bs[128 * 64];

  const int t = threadIdx.x;
  const int lane = t & 63, w = t >> 6;
  const int lr = lane & 15, g = lane >> 4;
  const int wr = w >> 1, wc = w & 1;
  const int row0 = blockIdx.x * 128;  // rows on fastest dim (XCD-local)
  const int col0 = blockIdx.y * 128;

  f32x4 acc[4][4];
#pragma unroll
  for (int m = 0; m < 4; ++m)
#pragma unroll
    for (int n = 0; n < 4; ++n) acc[m][n] = (f32x4){0.f, 0.f, 0.f, 0.f};

  for (int k0 = 0; k0 < H; k0 += 64) {
    __syncthreads();
    stage_tile(Ab, row0, k0, As, t);
    stage_tile(Bb, col0, k0, Bs, t);
    __syncthreads();
    wave_mma_step(As, Bs, wr, wc, lr, g, acc);
  }

#pragma unroll
  for (int m = 0; m < 4; ++m) {
    const int row = row0 + wr * 64 + m * 16 + 4 * g;
#pragma unroll
    for (int n = 0; n < 4; ++n) {
      const int col = col0 + wc * 64 + n * 16 + lr;
      const float bb = bias[col];
#pragma unroll
      for (int r = 0; r < 4; ++r)
        Y[(size_t)(row + r) * H + col] = acc[m][n][r] + bb;
    }
  }
}

// ---------------------------------------------------------------------------
// Swapped-operand 32x32x16 MFMA flash attention — R20: KEY-SPLIT occupancy.
// Total waves was invariant at 16/CU (131072 q / 32 q-per-wave / 256 CU).
// Now: block = 8 waves = 4 q-chunks x 2 KEY-HALVES; each wave does 32 q x
// 1024 keys -> 8192 waves -> 32/CU (VGPR 64 = 8 waves/SIMD, LDS 36.9KB x 4
// blocks = 147KB). Work is exactly unchanged (each key tile staged once per
// block; per-wave frag reads unchanged). Static-shift softmax (same -16 for
// both halves) makes the merge a PURE fp32 ADD of (oacc, l) — one LDS
// round-trip reusing Ks after the final barrier (stride-33 floats,
// conflict-free). No T14 prefetch (8 waves/SIMD TLP hides staging latency;
// frees 8 VGPRs for the 64-reg budget).
// QK: D[key][q] = mfma(A=K, B=Q); PV: D[d][q] = mfma(A=V^T, B=P).
// C/D map (m74/m101): col=lane&31, row=(reg&3)+8*(reg>>2)+4*(lane>>5).
// Grid (h, qt, b): same-head blocks spaced 16 ids -> same XCD -> L2-resident.
// ---------------------------------------------------------------------------
__global__ __launch_bounds__(512, 8) void attn_mfma(
    const u16* __restrict__ Q, const u16* __restrict__ K,
    const u16* __restrict__ VT, u16* __restrict__ CTX) {
  __shared__ u16 Ks[2][64][72];  // [kgrp][key][d]  144B rows, 0 conflicts
  __shared__ u16 Vs[2][64][72];  // [kgrp][d][key]

  const int t = threadIdx.x;
  const int lane = t & 63;
  const int w = t >> 6;        // wave 0..7
  const int l31 = lane & 31;
  const int hsel = lane >> 5;  // 0/1
  const int kgrp = w >> 2;     // key half: 0 -> [0,1024), 1 -> [1024,2048)
  const int wq = w & 3;        // q-chunk within block
  const int h = blockIdx.x, qt = blockIdx.y, b = blockIdx.z;

  const size_t base = (size_t)(b * NHEADS + h) * SEQ * HSZ;
  const u16* Qg = Q + base;
  const u16* Kg = K + base + (size_t)(kgrp * 1024) * HSZ;
  const u16* Vg = VT + base + kgrp * 1024;  // [64][SEQ], key-column offset
  const int q0 = qt * 128 + wq * 32;

  // Q B-frags: lane holds Q[q0+l31][16*ds+8*hsel+e]
  bf16x8 qf[4];
#pragma unroll
  for (int ds = 0; ds < 4; ++ds)
    qf[ds] = *(const bf16x8*)&Qg[(size_t)(q0 + l31) * HSZ + 16 * ds + 8 * hsel];

  f32x16 oacc[2];  // [dt]
#pragma unroll
  for (int dt = 0; dt < 2; ++dt)
#pragma unroll
    for (int r = 0; r < 16; ++r) oacc[dt][r] = 0.0f;
  float l_ = 0.0f;  // lane-local partial denominator

  // staging map within each 256-thread group (4 rows per thread via 2+2)
  const int t2 = t & 255;
  const int srow = t2 >> 3;       // 0..31
  const int scol = (t2 & 7) * 8;  // 0..56

  u16(*Kc)[72] = Ks[kgrp];
  u16(*Vc)[72] = Vs[kgrp];

  for (int kt = 0; kt < 16; ++kt) {
    __syncthreads();  // prev compute done with LDS
    *(uint4*)&Kc[srow][scol] =
        *(const uint4*)&Kg[(size_t)(kt * 64 + srow) * HSZ + scol];
    *(uint4*)&Kc[srow + 32][scol] =
        *(const uint4*)&Kg[(size_t)(kt * 64 + srow + 32) * HSZ + scol];
    *(uint4*)&Vc[srow][scol] =
        *(const uint4*)&Vg[(size_t)srow * SEQ + kt * 64 + scol];
    *(uint4*)&Vc[srow + 32][scol] =
        *(const uint4*)&Vg[(size_t)(srow + 32) * SEQ + kt * 64 + scol];
    __syncthreads();

#pragma unroll
    for (int ksub = 0; ksub < 2; ++ksub) {
      // K A-frags
      bf16x8 kf[4];
#pragma unroll
      for (int ds = 0; ds < 4; ++ds)
        kf[ds] = *(const bf16x8*)&Kc[32 * ksub + l31][16 * ds + 8 * hsel];
      // V^T A-frags [ks][dt]
      bf16x8 vf[2][2];
#pragma unroll
      for (int ks = 0; ks < 2; ++ks)
#pragma unroll
        for (int dt = 0; dt < 2; ++dt)
          vf[ks][dt] = *(const bf16x8*)&Vc[32 * dt + l31]
                                          [32 * ksub + 16 * ks + 8 * hsel];

      // QK^T (swapped): D[key][q]; acc pre-loaded with -16 => sacc = s-16
      f32x16 sacc;
#pragma unroll
      for (int r = 0; r < 16; ++r) sacc[r] = -16.0f;
#pragma unroll
      for (int ds = 0; ds < 4; ++ds)
        sacc = __builtin_amdgcn_mfma_f32_32x32x16_bf16(kf[ds], qf[ds], sacc,
                                                       0, 0, 0);

      // p = 2^(s-16); lane-local partial sum (no shuffles, no max)
      float p[16];
#pragma unroll
      for (int r = 0; r < 16; ++r) p[r] = __builtin_amdgcn_exp2f(sacc[r]);
      float s0 = (p[0] + p[1]) + (p[2] + p[3]);
      float s1 = (p[4] + p[5]) + (p[6] + p[7]);
      float s2 = (p[8] + p[9]) + (p[10] + p[11]);
      float s3 = (p[12] + p[13]) + (p[14] + p[15]);
      l_ += (s0 + s1) + (s2 + s3);

      // pack to bf16 pairs, permlane-swap into PV B-frags
      unsigned int pk[8];
#pragma unroll
      for (int i = 0; i < 8; ++i)
        asm("v_cvt_pk_bf16_f32 %0, %1, %2"
            : "=v"(pk[i])
            : "v"(p[2 * i]), "v"(p[2 * i + 1]));
      asm("v_permlane32_swap_b32 %0, %1" : "+v"(pk[0]), "+v"(pk[2]));
      asm("v_permlane32_swap_b32 %0, %1" : "+v"(pk[1]), "+v"(pk[3]));
      asm("v_permlane32_swap_b32 %0, %1" : "+v"(pk[4]), "+v"(pk[6]));
      asm("v_permlane32_swap_b32 %0, %1" : "+v"(pk[5]), "+v"(pk[7]));
      const bf16x8 pf0 =
          __builtin_bit_cast(bf16x8, (u32x4){pk[0], pk[1], pk[2], pk[3]});
      const bf16x8 pf1 =
          __builtin_bit_cast(bf16x8, (u32x4){pk[4], pk[5], pk[6], pk[7]});

      // PV (swapped): D[d][q] += V^T * P
#pragma unroll
      for (int dt = 0; dt < 2; ++dt) {
        oacc[dt] = __builtin_amdgcn_mfma_f32_32x32x16_bf16(vf[0][dt], pf0,
                                                           oacc[dt], 0, 0, 0);
        oacc[dt] = __builtin_amdgcn_mfma_f32_32x32x16_bf16(vf[1][dt], pf1,
                                                           oacc[dt], 0, 0, 0);
      }
    }
  }

  // key-half merge: group 1 publishes (oacc, l) via LDS; group 0 adds,
  // normalizes, writes. Static shift is identical -> pure fp32 add.
  __syncthreads();  // all compute done; K/V buffers free for reuse
  {
    float* mbuf = (float*)&Ks[0][0][0];  // 4*64*33 f32 = 33.8KB <= 36.9KB
    float* slot = &mbuf[(size_t)((wq << 6) + lane) * 33];
    if (kgrp == 1) {
#pragma unroll
      for (int dt = 0; dt < 2; ++dt)
#pragma unroll
        for (int r = 0; r < 16; ++r) slot[dt * 16 + r] = oacc[dt][r];
      slot[32] = l_;
    }
    __syncthreads();
    if (kgrp == 0) {
#pragma unroll
      for (int dt = 0; dt < 2; ++dt)
#pragma unroll
        for (int r = 0; r < 16; ++r) oacc[dt][r] += slot[dt * 16 + r];
      l_ += slot[32];

      const float lt = l_ + __shfl_xor(l_, 32);
      const float inv = 1.0f / lt;
      const int q = q0 + l31;
      u16* baseC = CTX + ((size_t)b * SEQ + q) * H + h * HSZ;
#pragma unroll
      for (int dt = 0; dt < 2; ++dt)
#pragma unroll
        for (int rg = 0; rg < 4; ++rg) {
          const int d0 = 32 * dt + 8 * rg + 4 * hsel;
          ushort4 vh;
          vh.x = f2bf(oacc[dt][4 * rg + 0] * inv);
          vh.y = f2bf(oacc[dt][4 * rg + 1] * inv);
          vh.z = f2bf(oacc[dt][4 * rg + 2] * inv);
          vh.w = f2bf(oacc[dt][4 * rg + 3] * inv);
          *(ushort4*)&baseC[d0] = vh;
        }
    }
  }
}

// ---------------------------------------------------------------------------
extern "C" void kernel_launch(void* const* d_in, const int* in_sizes, int n_in,
                              void* d_out, int out_size, void* d_ws,
                              size_t ws_size, hipStream_t stream) {
  const float* x = (const float*)d_in[0];
  const float* Wq = (const float*)d_in[1];
  const float* bq = (const float*)d_in[2];
  const float* Wk = (const float*)d_in[3];
  const float* bk = (const float*)d_in[4];
  const float* Wv = (const float*)d_in[5];
  const float* bv = (const float*)d_in[6];
  const float* Wo = (const float*)d_in[7];
  const float* bo = (const float*)d_in[8];

  const size_t PER = (size_t)4 * NHEADS * SEQ * HSZ;  // 8388608
  const size_t WSZ = (size_t)H * H;                   // 1048576
  u16* Qb = (u16*)d_ws;
  u16* Kb = Qb + PER;
  u16* VTb = Kb + PER;
  u16* CTXb = VTb + PER;
  u16* Xb = CTXb + PER;
  u16* Wqb = Xb + PER;
  u16* Wkb = Wqb + WSZ;
  u16* Wvb = Wkb + WSZ;
  u16* Wob = Wvb + WSZ;

  cast_all<<<dim3(512, 5), 256, 0, stream>>>(x, Wq, Wk, Wv, Wo, Xb, Wqb, Wkb,
                                             Wvb, Wob);

  // rows on blockIdx.x (XCD-local row stripes); V written transposed (z==2)
  qkv_mfma<<<dim3(NROWS / 128, H / 128, 3), 256, 0, stream>>>(
      Xb, Wqb, Wkb, Wvb, bq, bk, bv, Qb, Kb, VTb);

  // key-split: block covers 128 q x full SEQ (2 key-halves in-block)
  attn_mfma<<<dim3(NHEADS, SEQ / 128, 4), 512, 0, stream>>>(Qb, Kb, VTb,
                                                            CTXb);

  out_mfma<<<dim3(NROWS / 128, H / 128), 256, 0, stream>>>(CTXb, Wob, bo,
                                                           (float*)d_out);
}

// Round 21
// 177.437 us; speedup vs baseline: 6.5804x; 6.5804x over previous
//
#include <hip/hip_runtime.h>
#include <math.h>

#define H 1024
#define SEQ 2048
#define NHEADS 16
#define HSZ 64
#define NROWS 8192            // B*S = 4*2048
constexpr float SCALE = 0.125f;          // 1/sqrt(64)
constexpr float LOG2E = 1.44269504088896f;

typedef unsigned short u16;
typedef __attribute__((ext_vector_type(8))) short bf16x8;   // 8 bf16 (4 VGPRs)
typedef __attribute__((ext_vector_type(4))) float f32x4;    // 4 fp32
typedef __attribute__((ext_vector_type(16))) float f32x16;  // 32x32 acc
typedef __attribute__((ext_vector_type(4))) unsigned int u32x4;

__device__ __forceinline__ u16 f2bf(float f) {
  unsigned int u = __builtin_bit_cast(unsigned int, f);
  u = (u + 0x7fffu + ((u >> 16) & 1u)) >> 16;  // RNE
  return (u16)u;
}
__device__ __forceinline__ float bf2f(u16 h) {
  return __builtin_bit_cast(float, (unsigned int)h << 16);
}

// async global->LDS, 16B per lane. LDS dest = wave-uniform base + lane*16.
__device__ __forceinline__ void gload_lds16(const void* g, void* l) {
  unsigned long long ga = (unsigned long long)g;
  unsigned int la = (unsigned int)(unsigned long long)l;
  __builtin_amdgcn_global_load_lds(
      (const __attribute__((address_space(1))) unsigned int*)ga,
      (__attribute__((address_space(3))) unsigned int*)la, 16, 0, 0);
}

// ---------------------------------------------------------------------------
// Merged cast kernel (R18-verified piece): y=0 casts X, y=1..4 the weights.
// ---------------------------------------------------------------------------
__global__ __launch_bounds__(256) void cast_all(
    const float* __restrict__ x, const float* __restrict__ Wq,
    const float* __restrict__ Wk, const float* __restrict__ Wv,
    const float* __restrict__ Wo, u16* __restrict__ Xb, u16* __restrict__ Wqb,
    u16* __restrict__ Wkb, u16* __restrict__ Wvb, u16* __restrict__ Wob) {
  const int which = blockIdx.y;
  const float* src;
  u16* dst;
  int n4;
  if (which == 0) {
    src = x; dst = Xb; n4 = NROWS * H / 4;
  } else if (which == 1) {
    src = Wq; dst = Wqb; n4 = H * H / 4;
  } else if (which == 2) {
    src = Wk; dst = Wkb; n4 = H * H / 4;
  } else if (which == 3) {
    src = Wv; dst = Wvb; n4 = H * H / 4;
  } else {
    src = Wo; dst = Wob; n4 = H * H / 4;
  }
  for (int i = blockIdx.x * blockDim.x + threadIdx.x; i < n4;
       i += gridDim.x * blockDim.x) {
    float4 v = ((const float4*)src)[i];
    ushort4 o;
    o.x = f2bf(v.x); o.y = f2bf(v.y); o.z = f2bf(v.z); o.w = f2bf(v.w);
    ((ushort4*)dst)[i] = o;
  }
}

// ---------------------------------------------------------------------------
// MFMA GEMM (verified R4; R12 grid: blockIdx.x = row stripe -> XCD-local).
// ---------------------------------------------------------------------------
__device__ __forceinline__ void stage_tile(const u16* __restrict__ gbase,
                                           int row0, int k0,
                                           u16* __restrict__ lds, int t) {
  const int rl = t >> 3;
  const int sl = t & 7;
#pragma unroll
  for (int c = 0; c < 4; ++c) {
    const int r = c * 32 + rl;
    const int slot = sl ^ (r & 7);
    gload_lds16(gbase + (size_t)(row0 + r) * H + k0 + slot * 8,
                lds + (size_t)t * 8 + c * 2048);
  }
}

__device__ __forceinline__ void wave_frags(const u16* __restrict__ Ts, int w64,
                                           int lr, int g, int kk,
                                           bf16x8 f[4]) {
#pragma unroll
  for (int m = 0; m < 4; ++m) {
    const int row = w64 + m * 16 + lr;
    const int slot = (4 * kk + g) ^ (row & 7);
    f[m] = *(const bf16x8*)&Ts[row * 64 + slot * 8];
  }
}

__device__ __forceinline__ void wave_mma_step(const u16* As, const u16* Bs,
                                              int wr, int wc, int lr, int g,
                                              f32x4 acc[4][4]) {
#pragma unroll
  for (int kk = 0; kk < 2; ++kk) {
    bf16x8 af[4], bfr[4];
    wave_frags(As, wr * 64, lr, g, kk, af);
    wave_frags(Bs, wc * 64, lr, g, kk, bfr);
#pragma unroll
    for (int m = 0; m < 4; ++m)
#pragma unroll
      for (int n = 0; n < 4; ++n)
        acc[m][n] = __builtin_amdgcn_mfma_f32_16x16x32_bf16(af[m], bfr[n],
                                                            acc[m][n], 0, 0, 0);
  }
}

// QKV projection. z=0: Q (scaled, row-major [B,NH,S,HS]); z=1: K (row-major);
// z=2: V written DIRECTLY in transposed [B,NH,HS,S] layout (ushort4 stores).
__global__ __launch_bounds__(256) void qkv_mfma(
    const u16* __restrict__ Xb, const u16* __restrict__ Wqb,
    const u16* __restrict__ Wkb, const u16* __restrict__ Wvb,
    const float* __restrict__ bq, const float* __restrict__ bk,
    const float* __restrict__ bv, u16* __restrict__ Qo, u16* __restrict__ Ko,
    u16* __restrict__ VTo) {
  __shared__ u16 As[128 * 64];
  __shared__ u16 Bs[128 * 64];

  const u16* Wb;
  const float* bias;
  float scale = 1.0f;
  if (blockIdx.z == 0) {
    Wb = Wqb; bias = bq; scale = SCALE * LOG2E;  // exp2-domain scores
  } else if (blockIdx.z == 1) {
    Wb = Wkb; bias = bk;
  } else {
    Wb = Wvb; bias = bv;
  }

  const int t = threadIdx.x;
  const int lane = t & 63, w = t >> 6;
  const int lr = lane & 15, g = lane >> 4;
  const int wr = w >> 1, wc = w & 1;
  const int row0 = blockIdx.x * 128;  // rows on fastest dim (XCD-local)
  const int col0 = blockIdx.y * 128;

  f32x4 acc[4][4];
#pragma unroll
  for (int m = 0; m < 4; ++m)
#pragma unroll
    for (int n = 0; n < 4; ++n) acc[m][n] = (f32x4){0.f, 0.f, 0.f, 0.f};

  for (int k0 = 0; k0 < H; k0 += 64) {
    __syncthreads();
    stage_tile(Xb, row0, k0, As, t);
    stage_tile(Wb, col0, k0, Bs, t);
    __syncthreads();
    wave_mma_step(As, Bs, wr, wc, lr, g, acc);
  }

  if (blockIdx.z == 2) {
    // V -> VT [B,NH,HS,S]: 4 consecutive s per acc vector -> ushort4
#pragma unroll
    for (int m = 0; m < 4; ++m) {
      const int row = row0 + wr * 64 + m * 16 + 4 * g;  // s0 (mult of 4)
      const int b = row >> 11, s = row & 2047;
#pragma unroll
      for (int n = 0; n < 4; ++n) {
        const int col = col0 + wc * 64 + n * 16 + lr;
        const int head = col >> 6, hs = col & 63;
        const float bb = bias[col];
        ushort4 sv;
        sv.x = f2bf(acc[m][n][0] + bb);
        sv.y = f2bf(acc[m][n][1] + bb);
        sv.z = f2bf(acc[m][n][2] + bb);
        sv.w = f2bf(acc[m][n][3] + bb);
        *(ushort4*)&VTo[((size_t)(b * NHEADS + head) * HSZ + hs) * SEQ + s] =
            sv;
      }
    }
  } else {
    u16* Y = blockIdx.z == 0 ? Qo : Ko;
#pragma unroll
    for (int m = 0; m < 4; ++m) {
      const int row = row0 + wr * 64 + m * 16 + 4 * g;
#pragma unroll
      for (int n = 0; n < 4; ++n) {
        const int col = col0 + wc * 64 + n * 16 + lr;
        const int head = col >> 6, hs = col & 63;
        const float bb = bias[col];
#pragma unroll
        for (int r = 0; r < 4; ++r) {
          const int rr = row + r;
          const int b = rr >> 11, s = rr & 2047;
          Y[((size_t)(b * NHEADS + head) * SEQ + s) * HSZ + hs] =
              f2bf((acc[m][n][r] + bb) * scale);
        }
      }
    }
  }
}

// Out projection: plain bf16 GEMM (R17), fp32 output + bias.
__global__ __launch_bounds__(256) void out_mfma(
    const u16* __restrict__ Ab, const u16* __restrict__ Bb,
    const float* __restrict__ bias, float* __restrict__ Y) {
  __shared__ u16 As[128 * 64];
  __shared__ u16 Bs[128 * 64];

  const int t = threadIdx.x;
  const int lane = t & 63, w = t >> 6;
  const int lr = lane & 15, g = lane >> 4;
  const int wr = w >> 1, wc = w & 1;
  const int row0 = blockIdx.x * 128;  // rows on fastest dim (XCD-local)
  const int col0 = blockIdx.y * 128;

  f32x4 acc[4][4];
#pragma unroll
  for (int m = 0; m < 4; ++m)
#pragma unroll
    for (int n = 0; n < 4; ++n) acc[m][n] = (f32x4){0.f, 0.f, 0.f, 0.f};

  for (int k0 = 0; k0 < H; k0 += 64) {
    __syncthreads();
    stage_tile(Ab, row0, k0, As, t);
    stage_tile(Bb, col0, k0, Bs, t);
    __syncthreads();
    wave_mma_step(As, Bs, wr, wc, lr, g, acc);
  }

#pragma unroll
  for (int m = 0; m < 4; ++m) {
    const int row = row0 + wr * 64 + m * 16 + 4 * g;
#pragma unroll
    for (int n = 0; n < 4; ++n) {
      const int col = col0 + wc * 64 + n * 16 + lr;
      const float bb = bias[col];
#pragma unroll
      for (int r = 0; r < 4; ++r)
        Y[(size_t)(row + r) * H + col] = acc[m][n][r] + bb;
    }
  }
}

// ---------------------------------------------------------------------------
// Swapped-operand 32x32x16 MFMA flash attention — R21 (= R19/R17 verbatim,
// the 77 us known-good: 8 waves x 32 q, dbuf LDS single barrier, scalar
// kreg/vreg prefetch, static-shift softmax, single bf16 ctx plane).
// R20's key-split (launch_bounds 512,8) capped VGPR at 32 -> total spill;
// this structure needs ~64 live VGPRs/wave, i.e. max 4 waves/SIMD.
// QK: D[key][q] = mfma(A=K, B=Q); PV: D[d][q] = mfma(A=V^T, B=P).
// C/D map (m74/m101): col=lane&31, row=(reg&3)+8*(reg>>2)+4*(lane>>5).
// Grid (h, qt, b): same-head blocks -> same XCD -> K/V L2-resident.
// ---------------------------------------------------------------------------
__global__ __launch_bounds__(512, 4) void attn_mfma(
    const u16* __restrict__ Q, const u16* __restrict__ K,
    const u16* __restrict__ VT, u16* __restrict__ CTX) {
  __shared__ u16 Ks[2][64][72];  // [buf][key][d]  pad->144B rows, 0 conflicts
  __shared__ u16 Vs[2][64][72];  // [buf][d][key]

  const int t = threadIdx.x;
  const int lane = t & 63;
  const int w = t >> 6;        // wave 0..7
  const int l31 = lane & 31;
  const int hsel = lane >> 5;  // 0/1
  const int h = blockIdx.x, qt = blockIdx.y, b = blockIdx.z;

  const size_t base = (size_t)(b * NHEADS + h) * SEQ * HSZ;
  const u16* Qg = Q + base;
  const u16* Kg = K + base;
  const u16* Vg = VT + base;  // [64][SEQ]
  const int q0 = qt * 256 + w * 32;

  // Q B-frags: lane holds Q[q0+l31][16*ds+8*hsel+e]
  bf16x8 qf[4];
#pragma unroll
  for (int ds = 0; ds < 4; ++ds)
    qf[ds] = *(const bf16x8*)&Qg[(size_t)(q0 + l31) * HSZ + 16 * ds + 8 * hsel];

  f32x16 oacc[2];  // [dt]
#pragma unroll
  for (int dt = 0; dt < 2; ++dt)
#pragma unroll
    for (int r = 0; r < 16; ++r) oacc[dt][r] = 0.0f;
  float l_ = 0.0f;  // lane-local partial denominator

  const int srow = t >> 3;       // 0..63 staging row (512 threads)
  const int scol = (t & 7) * 8;  // 0..56

  // T14 prologue: tile 0 into NAMED scalar regs
  uint4 kreg = *(const uint4*)&Kg[(size_t)srow * HSZ + scol];
  uint4 vreg = *(const uint4*)&Vg[(size_t)srow * SEQ + scol];

  for (int kt = 0; kt < SEQ / 64; ++kt) {
    u16(*Kc)[72] = Ks[kt & 1];
    u16(*Vc)[72] = Vs[kt & 1];
    *(uint4*)&Kc[srow][scol] = kreg;
    *(uint4*)&Vc[srow][scol] = vreg;
    __syncthreads();  // single barrier: buf ready; other buf free to write

    // issue next tile's loads; they fly during this tile's compute
    if (kt + 1 < SEQ / 64) {
      kreg = *(const uint4*)&Kg[(size_t)((kt + 1) * 64 + srow) * HSZ + scol];
      vreg =
          *(const uint4*)&Vg[(size_t)srow * SEQ + (size_t)(kt + 1) * 64 + scol];
    }

#pragma unroll
    for (int ksub = 0; ksub < 2; ++ksub) {
      // K A-frags
      bf16x8 kf[4];
#pragma unroll
      for (int ds = 0; ds < 4; ++ds)
        kf[ds] = *(const bf16x8*)&Kc[32 * ksub + l31][16 * ds + 8 * hsel];
      // V^T A-frags [ks][dt]
      bf16x8 vf[2][2];
#pragma unroll
      for (int ks = 0; ks < 2; ++ks)
#pragma unroll
        for (int dt = 0; dt < 2; ++dt)
          vf[ks][dt] = *(const bf16x8*)&Vc[32 * dt + l31]
                                          [32 * ksub + 16 * ks + 8 * hsel];

      // QK^T (swapped): D[key][q]; acc pre-loaded with -16 => sacc = s-16
      f32x16 sacc;
#pragma unroll
      for (int r = 0; r < 16; ++r) sacc[r] = -16.0f;
#pragma unroll
      for (int ds = 0; ds < 4; ++ds)
        sacc = __builtin_amdgcn_mfma_f32_32x32x16_bf16(kf[ds], qf[ds], sacc,
                                                       0, 0, 0);

      // p = 2^(s-16); lane-local partial sum (no shuffles, no max)
      float p[16];
#pragma unroll
      for (int r = 0; r < 16; ++r) p[r] = __builtin_amdgcn_exp2f(sacc[r]);
      float s0 = (p[0] + p[1]) + (p[2] + p[3]);
      float s1 = (p[4] + p[5]) + (p[6] + p[7]);
      float s2 = (p[8] + p[9]) + (p[10] + p[11]);
      float s3 = (p[12] + p[13]) + (p[14] + p[15]);
      l_ += (s0 + s1) + (s2 + s3);

      // pack to bf16 pairs, permlane-swap into PV B-frags
      unsigned int pk[8];
#pragma unroll
      for (int i = 0; i < 8; ++i)
        asm("v_cvt_pk_bf16_f32 %0, %1, %2"
            : "=v"(pk[i])
            : "v"(p[2 * i]), "v"(p[2 * i + 1]));
      asm("v_permlane32_swap_b32 %0, %1" : "+v"(pk[0]), "+v"(pk[2]));
      asm("v_permlane32_swap_b32 %0, %1" : "+v"(pk[1]), "+v"(pk[3]));
      asm("v_permlane32_swap_b32 %0, %1" : "+v"(pk[4]), "+v"(pk[6]));
      asm("v_permlane32_swap_b32 %0, %1" : "+v"(pk[5]), "+v"(pk[7]));
      const bf16x8 pf0 =
          __builtin_bit_cast(bf16x8, (u32x4){pk[0], pk[1], pk[2], pk[3]});
      const bf16x8 pf1 =
          __builtin_bit_cast(bf16x8, (u32x4){pk[4], pk[5], pk[6], pk[7]});

      // PV (swapped): D[d][q] += V^T * P
#pragma unroll
      for (int dt = 0; dt < 2; ++dt) {
        oacc[dt] = __builtin_amdgcn_mfma_f32_32x32x16_bf16(vf[0][dt], pf0,
                                                           oacc[dt], 0, 0, 0);
        oacc[dt] = __builtin_amdgcn_mfma_f32_32x32x16_bf16(vf[1][dt], pf1,
                                                           oacc[dt], 0, 0, 0);
      }
    }
  }

  // epilogue: single cross-half reduce of l, normalize, emit bf16 ctx
  {
    const float lt = l_ + __shfl_xor(l_, 32);
    const float inv = 1.0f / lt;
    const int q = q0 + l31;
    u16* baseC = CTX + ((size_t)b * SEQ + q) * H + h * HSZ;
#pragma unroll
    for (int dt = 0; dt < 2; ++dt)
#pragma unroll
      for (int rg = 0; rg < 4; ++rg) {
        const int d0 = 32 * dt + 8 * rg + 4 * hsel;
        ushort4 vh;
        vh.x = f2bf(oacc[dt][4 * rg + 0] * inv);
        vh.y = f2bf(oacc[dt][4 * rg + 1] * inv);
        vh.z = f2bf(oacc[dt][4 * rg + 2] * inv);
        vh.w = f2bf(oacc[dt][4 * rg + 3] * inv);
        *(ushort4*)&baseC[d0] = vh;
      }
  }
}

// ---------------------------------------------------------------------------
extern "C" void kernel_launch(void* const* d_in, const int* in_sizes, int n_in,
                              void* d_out, int out_size, void* d_ws,
                              size_t ws_size, hipStream_t stream) {
  const float* x = (const float*)d_in[0];
  const float* Wq = (const float*)d_in[1];
  const float* bq = (const float*)d_in[2];
  const float* Wk = (const float*)d_in[3];
  const float* bk = (const float*)d_in[4];
  const float* Wv = (const float*)d_in[5];
  const float* bv = (const float*)d_in[6];
  const float* Wo = (const float*)d_in[7];
  const float* bo = (const float*)d_in[8];

  const size_t PER = (size_t)4 * NHEADS * SEQ * HSZ;  // 8388608
  const size_t WSZ = (size_t)H * H;                   // 1048576
  u16* Qb = (u16*)d_ws;
  u16* Kb = Qb + PER;
  u16* VTb = Kb + PER;
  u16* CTXb = VTb + PER;
  u16* Xb = CTXb + PER;
  u16* Wqb = Xb + PER;
  u16* Wkb = Wqb + WSZ;
  u16* Wvb = Wkb + WSZ;
  u16* Wob = Wvb + WSZ;

  cast_all<<<dim3(512, 5), 256, 0, stream>>>(x, Wq, Wk, Wv, Wo, Xb, Wqb, Wkb,
                                             Wvb, Wob);

  // rows on blockIdx.x (XCD-local row stripes); V written transposed (z==2)
  qkv_mfma<<<dim3(NROWS / 128, H / 128, 3), 256, 0, stream>>>(
      Xb, Wqb, Wkb, Wvb, bq, bk, bv, Qb, Kb, VTb);

  attn_mfma<<<dim3(NHEADS, SEQ / 256, 4), 512, 0, stream>>>(Qb, Kb, VTb,
                                                            CTXb);

  out_mfma<<<dim3(NROWS / 128, H / 128), 256, 0, stream>>>(CTXb, Wob, bo,
                                                           (float*)d_out);
}